// Round 5
// baseline (158.076 us; speedup 1.0000x reference)
//
#include <hip/hip_runtime.h>

// Problem constants
#define MATN   2048
#define NTRIU  2098176           // 2048*2049/2
#define NBATCH 32

// Tiles: one wave (64 lanes) handles a 256-column segment of one row.
// 8 tiles per row, 2048 rows, 32 batches -> 524288 tiles.
#define NTILES (NBATCH * MATN * 8)

// clang-native float4; the 'u' variant is 4B-aligned so clang emits
// global_load_dwordx4 on dword-aligned (not 16B-aligned) addresses,
// which gfx950 hardware supports.
typedef float f32x4  __attribute__((ext_vector_type(4)));
typedef float f32x4u __attribute__((ext_vector_type(4), aligned(4)));

// Lane l covers columns c0 = seg + 4l .. c0+3 of row r:
//  - one (possibly 4B-aligned) dwordx4 load of 4 consecutive triu inputs
//  - one aligned 16B nontemporal dwordx4 store
// 1 load + 1 store per 1KiB wave-tile; no LDS; iterations independent,
// so the compiler can software-pipeline loads across tiles.

__global__ __launch_bounds__(256)
void triu_scatter_kernel(const float* __restrict__ in, float* __restrict__ out) {
    const int lane   = threadIdx.x & 63;
    const int warp   = (blockIdx.x * blockDim.x + threadIdx.x) >> 6;
    const int nwarps = (gridDim.x * blockDim.x) >> 6;

    for (int tile = warp; tile < NTILES; tile += nwarps) {
        const int b   = tile >> 14;           // / (2048*8)
        const int rem = tile & 16383;
        const int r   = rem >> 3;             // row
        const int seg = (rem & 7) << 8;       // starting column of 256-wide segment
        const int c0  = seg + (lane << 2);    // this lane's first column

        const int g = b * NTRIU + r * MATN - ((r * (r - 1)) >> 1) - r;
        const int out_base = ((b << 11) + r) << 11;   // (b*2048 + r)*2048

        f32x4 v;
        if (seg >= r) {
            // tile fully in upper triangle (wave-uniform branch)
            v = *reinterpret_cast<const f32x4u*>(in + g + c0);
        } else if (seg + 255 < r) {
            // tile fully below diagonal (wave-uniform branch)
            v = (f32x4){0.f, 0.f, 0.f, 0.f};
        } else {
            // diagonal-straddling tile (one per row): per-lane handling
            if (c0 >= r) {
                v = *reinterpret_cast<const f32x4u*>(in + g + c0);
            } else if (c0 + 3 < r) {
                v = (f32x4){0.f, 0.f, 0.f, 0.f};
            } else {
                v.x = (c0 + 0 >= r) ? in[g + c0 + 0] : 0.f;
                v.y = (c0 + 1 >= r) ? in[g + c0 + 1] : 0.f;
                v.z = (c0 + 2 >= r) ? in[g + c0 + 2] : 0.f;
                v.w = (c0 + 3 >= r) ? in[g + c0 + 3] : 0.f;
            }
        }
        __builtin_nontemporal_store(
            v, reinterpret_cast<f32x4*>(out + out_base + c0));
    }
}

extern "C" void kernel_launch(void* const* d_in, const int* in_sizes, int n_in,
                              void* d_out, int out_size, void* d_ws, size_t ws_size,
                              hipStream_t stream) {
    const float* in = (const float*)d_in[0];
    float* out = (float*)d_out;

    const int block = 256;
    const int grid  = 4096;   // 16384 waves -> 32 tiles/wave, grid-stride
    triu_scatter_kernel<<<grid, block, 0, stream>>>(in, out);
}

// Round 6
// 156.142 us; speedup vs baseline: 1.0124x; 1.0124x over previous
//
#include <hip/hip_runtime.h>

// Problem constants
#define MATN   2048
#define NTRIU  2098176           // 2048*2049/2 (divisible by 4)
#define NBATCH 32

// Tiles: one wave (64 lanes) handles a 256-column segment of one row.
#define NTILES (NBATCH * MATN * 8)

typedef float f32x4 __attribute__((ext_vector_type(4)));

// Gather tiles: load 16B-ALIGNED dwordx4 from A = (g+seg)&~3, then rotate the
// wave's 256-dword window left by m = (g+seg)&3 dwords using cross-lane
// shuffles (lane l takes v[m..3] of itself + v[0..m-1] of lane l+1).
// Lane 63's spill-over comes from one predicated aligned load at A+256.
// Stores: aligned 16B nontemporal dwordx4. No LDS, no barriers.

__global__ __launch_bounds__(256)
void triu_scatter_kernel(const float* __restrict__ in, float* __restrict__ out) {
    const int lane   = threadIdx.x & 63;
    const int warp   = (blockIdx.x * blockDim.x + threadIdx.x) >> 6;
    const int nwarps = (gridDim.x * blockDim.x) >> 6;

    for (int tile = warp; tile < NTILES; tile += nwarps) {
        const int b   = tile >> 14;           // / (2048*8)
        const int rem = tile & 16383;
        const int r   = rem >> 3;             // row
        const int seg = (rem & 7) << 8;       // starting column of 256-wide segment
        const int c0  = seg + (lane << 2);    // this lane's first output column

        const int g = b * NTRIU + r * MATN - ((r * (r - 1)) >> 1) - r;
        const int out_base = ((b << 11) + r) << 11;   // (b*2048 + r)*2048

        f32x4 o;
        if (seg >= r) {
            // --- pure gather tile (wave-uniform) ---
            const int s = g + seg;            // wave-uniform input start
            const int m = s & 3;              // wave-uniform misalignment
            const float* __restrict__ pA = in + (s - m);   // 16B-aligned base
            f32x4 v = *reinterpret_cast<const f32x4*>(pA + (lane << 2));
            if (m == 0) {
                o = v;
            } else {
                f32x4 t = {0.f, 0.f, 0.f, 0.f};
                if (lane == 63)               // aligned tail chunk, in-bounds
                    t = *reinterpret_cast<const f32x4*>(pA + 256);
                const int src = (lane + 1) & 63;
                float w0 = __shfl(v.x, src, 64); if (lane == 63) w0 = t.x;
                if (m == 1) {
                    o = (f32x4){v.y, v.z, v.w, w0};
                } else {
                    float w1 = __shfl(v.y, src, 64); if (lane == 63) w1 = t.y;
                    if (m == 2) {
                        o = (f32x4){v.z, v.w, w0, w1};
                    } else {
                        float w2 = __shfl(v.z, src, 64); if (lane == 63) w2 = t.z;
                        o = (f32x4){v.w, w0, w1, w2};
                    }
                }
            }
        } else if (seg + 255 < r) {
            // --- fully below diagonal (wave-uniform) ---
            o = (f32x4){0.f, 0.f, 0.f, 0.f};
        } else {
            // --- diagonal-straddling tile (one per row): per-lane scalar ---
            o.x = (c0 + 0 >= r) ? in[g + c0 + 0] : 0.f;
            o.y = (c0 + 1 >= r) ? in[g + c0 + 1] : 0.f;
            o.z = (c0 + 2 >= r) ? in[g + c0 + 2] : 0.f;
            o.w = (c0 + 3 >= r) ? in[g + c0 + 3] : 0.f;
        }
        __builtin_nontemporal_store(
            o, reinterpret_cast<f32x4*>(out + out_base + c0));
    }
}

extern "C" void kernel_launch(void* const* d_in, const int* in_sizes, int n_in,
                              void* d_out, int out_size, void* d_ws, size_t ws_size,
                              hipStream_t stream) {
    const float* in = (const float*)d_in[0];
    float* out = (float*)d_out;

    const int block = 256;
    const int grid  = 4096;   // 16384 waves -> 32 tiles/wave, grid-stride
    triu_scatter_kernel<<<grid, block, 0, stream>>>(in, out);
}

// Round 7
// 117.274 us; speedup vs baseline: 1.3479x; 1.3314x over previous
//
#include <hip/hip_runtime.h>

// Problem constants
#define MATN   2048
#define NTRIU  2098176           // 2048*2049/2
#define NBATCH 32

// Tiles: one wave (64 lanes) handles a 512-column segment of one row.
// 4 tiles per row, 2048 rows, 32 batches -> 262144 tiles.
#define NTILES (NBATCH * MATN * 4)

typedef float f32x4 __attribute__((ext_vector_type(4)));

// Per wave-iteration (2 KiB of output):
//  1) 8 independent contiguous scalar loads issue back-to-back (MLP x2 vs R4)
//  2) wave-private 2 KiB LDS repack (same-wave DS ops are ordered; no barrier)
//  3) two aligned 16B/lane nontemporal dwordx4 stores

__global__ __launch_bounds__(256)
void triu_scatter_kernel(const float* __restrict__ in, float* __restrict__ out) {
    __shared__ float lbuf[4][512];            // 2 KiB per wave, 4 waves/block
    const int lane   = threadIdx.x & 63;
    const int wid    = threadIdx.x >> 6;
    const int warp   = (blockIdx.x * blockDim.x + threadIdx.x) >> 6;
    const int nwarps = (gridDim.x * blockDim.x) >> 6;
    float* __restrict__ lw = lbuf[wid];

    for (int tile = warp; tile < NTILES; tile += nwarps) {
        const int b   = tile >> 13;           // / (2048*4)
        const int rem = tile & 8191;
        const int r   = rem >> 2;             // row
        const int seg = (rem & 3) << 9;       // starting column of 512-wide segment

        const int g = b * NTRIU + r * MATN - ((r * (r - 1)) >> 1) - r;
        const int out_base = ((b << 11) + r) << 11;   // (b*2048 + r)*2048

        // 1) gather: lane l covers columns seg + 64k + l, k = 0..7
        float v[8];
        if (seg >= r) {
            // fully in upper triangle (wave-uniform): unconditional loads
            const float* __restrict__ p = in + g + seg + lane;
            #pragma unroll
            for (int k = 0; k < 8; ++k) v[k] = p[k << 6];
        } else if (seg + 511 < r) {
            #pragma unroll
            for (int k = 0; k < 8; ++k) v[k] = 0.f;
        } else {
            // diagonal-straddling segment (one per row)
            #pragma unroll
            for (int k = 0; k < 8; ++k) {
                const int c = seg + (k << 6) + lane;
                v[k] = (c >= r) ? in[g + c] : 0.f;
            }
        }
        // 2) LDS repack: write lane-contiguous, read b128
        #pragma unroll
        for (int k = 0; k < 8; ++k)
            lw[(k << 6) + lane] = v[k];
        const f32x4 o0 = *reinterpret_cast<const f32x4*>(&lw[lane << 2]);
        const f32x4 o1 = *reinterpret_cast<const f32x4*>(&lw[256 + (lane << 2)]);
        // 3) two aligned 16B/lane nontemporal stores
        float* __restrict__ ob = out + out_base + seg;
        __builtin_nontemporal_store(o0, reinterpret_cast<f32x4*>(ob + (lane << 2)));
        __builtin_nontemporal_store(o1, reinterpret_cast<f32x4*>(ob + 256 + (lane << 2)));
    }
}

extern "C" void kernel_launch(void* const* d_in, const int* in_sizes, int n_in,
                              void* d_out, int out_size, void* d_ws, size_t ws_size,
                              hipStream_t stream) {
    const float* in = (const float*)d_in[0];
    float* out = (float*)d_out;

    const int block = 256;
    const int grid  = 4096;   // 16384 waves -> 16 tiles/wave, grid-stride
    triu_scatter_kernel<<<grid, block, 0, stream>>>(in, out);
}

// Round 8
// 113.966 us; speedup vs baseline: 1.3870x; 1.0290x over previous
//
#include <hip/hip_runtime.h>

// Problem constants
#define MATN   2048
#define NTRIU  2098176           // 2048*2049/2
#define NBATCH 32

// Tiles: one wave (64 lanes) handles a 1024-column segment of one row.
// 2 tiles per row, 2048 rows, 32 batches -> 131072 tiles.
#define NTILES (NBATCH * MATN * 2)

typedef float f32x4 __attribute__((ext_vector_type(4)));

// Per wave-iteration (4 KiB of output):
//  1) 16 independent contiguous scalar loads issue back-to-back (MLP x2 vs R7)
//  2) wave-private 4 KiB LDS repack (same-wave DS ops are ordered; no barrier)
//  3) four aligned 16B/lane nontemporal dwordx4 stores

__global__ __launch_bounds__(256)
void triu_scatter_kernel(const float* __restrict__ in, float* __restrict__ out) {
    __shared__ float lbuf[4][1024];           // 4 KiB per wave, 4 waves/block
    const int lane   = threadIdx.x & 63;
    const int wid    = threadIdx.x >> 6;
    const int warp   = (blockIdx.x * blockDim.x + threadIdx.x) >> 6;
    const int nwarps = (gridDim.x * blockDim.x) >> 6;
    float* __restrict__ lw = lbuf[wid];

    for (int tile = warp; tile < NTILES; tile += nwarps) {
        const int b   = tile >> 12;           // / (2048*2)
        const int rem = tile & 4095;
        const int r   = rem >> 1;             // row
        const int seg = (rem & 1) << 10;      // starting column of 1024-wide segment

        const int g = b * NTRIU + r * MATN - ((r * (r - 1)) >> 1) - r;
        const int out_base = ((b << 11) + r) << 11;   // (b*2048 + r)*2048

        // 1) gather: lane l covers columns seg + 64k + l, k = 0..15
        float v[16];
        if (seg >= r) {
            // fully in upper triangle (wave-uniform): unconditional loads
            const float* __restrict__ p = in + g + seg + lane;
            #pragma unroll
            for (int k = 0; k < 16; ++k) v[k] = p[k << 6];
        } else if (seg + 1023 < r) {
            #pragma unroll
            for (int k = 0; k < 16; ++k) v[k] = 0.f;
        } else {
            // diagonal-straddling segment: predicated per-lane loads
            #pragma unroll
            for (int k = 0; k < 16; ++k) {
                const int c = seg + (k << 6) + lane;
                v[k] = (c >= r) ? in[g + c] : 0.f;
            }
        }
        // 2) LDS repack: write lane-contiguous, read b128
        #pragma unroll
        for (int k = 0; k < 16; ++k)
            lw[(k << 6) + lane] = v[k];
        // 3) four aligned 16B/lane nontemporal stores
        float* __restrict__ ob = out + out_base + seg;
        #pragma unroll
        for (int q = 0; q < 4; ++q) {
            const f32x4 o = *reinterpret_cast<const f32x4*>(&lw[(q << 8) + (lane << 2)]);
            __builtin_nontemporal_store(
                o, reinterpret_cast<f32x4*>(ob + (q << 8) + (lane << 2)));
        }
    }
}

extern "C" void kernel_launch(void* const* d_in, const int* in_sizes, int n_in,
                              void* d_out, int out_size, void* d_ws, size_t ws_size,
                              hipStream_t stream) {
    const float* in = (const float*)d_in[0];
    float* out = (float*)d_out;

    const int block = 256;
    const int grid  = 4096;   // 16384 waves -> 8 tiles/wave, grid-stride
    triu_scatter_kernel<<<grid, block, 0, stream>>>(in, out);
}